// Round 16
// baseline (190.283 us; speedup 1.0000x reference)
//
#include <hip/hip_runtime.h>
#include <math.h>

typedef __bf16 bf16x8 __attribute__((ext_vector_type(8)));
typedef float  f32x4  __attribute__((ext_vector_type(4)));
typedef unsigned short u16x8 __attribute__((ext_vector_type(8)));

__device__ __forceinline__ float bf2f(unsigned short u) {
    return __uint_as_float(((unsigned int)u) << 16);
}
__device__ __forceinline__ unsigned short f2bf_n(float f) {
    return __builtin_bit_cast(unsigned short, (__bf16)f);  // native cvt (RNE)
}
__device__ __forceinline__ void gl_lds16(const unsigned short* g, unsigned short* l) {
    __builtin_amdgcn_global_load_lds(
        (const __attribute__((address_space(1))) unsigned int*)g,
        (__attribute__((address_space(3))) unsigned int*)l, 16, 0, 0);
}

// dims
#define BATCH 4
#define SEQ 512
#define DM 1024
#define NH 16
#define DH 64
#define DFF 4096
#define MROWS (BATCH * SEQ)   // 2048

__global__ __launch_bounds__(256) void fill0_kernel(float* __restrict__ out) {
    out[blockIdx.x * 256 + threadIdx.x] = 0.0f;
}

// ---------------- weight transpose+convert: in[K][N] f32 -> out[N][K] bf16 ----------
__global__ __launch_bounds__(256) void tconv_kernel(const float* __restrict__ in,
                                                    unsigned short* __restrict__ out,
                                                    int K, int N) {
    __shared__ float tile[64][33];
    const int n0 = blockIdx.x * 32, k0 = blockIdx.y * 64;
    const int t = threadIdx.x;
    const int tx = t & 31, ty = t >> 5;
    #pragma unroll
    for (int i = 0; i < 8; ++i)
        tile[ty + i * 8][tx] = in[(size_t)(k0 + ty + i * 8) * N + n0 + tx];
    __syncthreads();
    const int nr = t >> 3;
    const int ks = (t & 7) * 8;
    u16x8 v;
    #pragma unroll
    for (int j = 0; j < 8; ++j) v[j] = f2bf_n(tile[ks + j][nr]);
    *(u16x8*)&out[(size_t)(n0 + nr) * K + k0 + ks] = v;
}

// fused 4x (1024x1024) transpose
__global__ __launch_bounds__(256) void tconv4_kernel(const float* __restrict__ i0,
                                                     const float* __restrict__ i1,
                                                     const float* __restrict__ i2,
                                                     const float* __restrict__ i3,
                                                     unsigned short* __restrict__ o0,
                                                     unsigned short* __restrict__ o1,
                                                     unsigned short* __restrict__ o2,
                                                     unsigned short* __restrict__ o3) {
    const int z = blockIdx.z;
    const float* in = (z == 0) ? i0 : (z == 1) ? i1 : (z == 2) ? i2 : i3;
    unsigned short* out = (z == 0) ? o0 : (z == 1) ? o1 : (z == 2) ? o2 : o3;
    __shared__ float tile[64][33];
    const int n0 = blockIdx.x * 32, k0 = blockIdx.y * 64;
    const int t = threadIdx.x;
    const int tx = t & 31, ty = t >> 5;
    #pragma unroll
    for (int i = 0; i < 8; ++i)
        tile[ty + i * 8][tx] = in[(size_t)(k0 + ty + i * 8) * 1024 + n0 + tx];
    __syncthreads();
    const int nr = t >> 3;
    const int ks = (t & 7) * 8;
    u16x8 v;
    #pragma unroll
    for (int j = 0; j < 8; ++j) v[j] = f2bf_n(tile[ks + j][nr]);
    *(u16x8*)&out[(size_t)(n0 + nr) * 1024 + k0 + ks] = v;
}

// ---------------- 1) sinusoidal emb + silu ----------------
__global__ void semb_kernel(const int* __restrict__ ts, float* __restrict__ semb) {
    int b = blockIdx.x;
    float x = (float)ts[b] * 40.0f;
    for (int j = threadIdx.x; j < 1024; j += 256) {
        int idx = (j < 512) ? j : (j - 512);
        float fr = expf(-9.210340371976184f * (float)idx / 511.0f);
        float e = x * fr;
        float v = (j < 512) ? sinf(e) : cosf(e);
        semb[b * 1024 + j] = v / (1.0f + expf(-v));
    }
}

// ---------------- 2a) ada partials ----------------
__global__ __launch_bounds__(256) void ada_part_kernel(const float* __restrict__ semb,
                                                       const float* __restrict__ W,
                                                       float* __restrict__ part) {
    const int nb = blockIdx.x, kc = blockIdx.y;
    const int t = threadIdx.x;
    __shared__ float e_s[4][64];
    e_s[t >> 6][t & 63] = semb[(t >> 6) * 1024 + kc * 64 + (t & 63)];
    __syncthreads();
    const int n = nb * 128 + (t & 127);
    const int half = t >> 7;
    float a0 = 0.f, a1 = 0.f, a2 = 0.f, a3 = 0.f;
    const int kk0 = half * 32;
    #pragma unroll 8
    for (int kk = kk0; kk < kk0 + 32; ++kk) {
        const float w = W[(size_t)(kc * 64 + kk) * 2048 + n];
        a0 += e_s[0][kk] * w; a1 += e_s[1][kk] * w;
        a2 += e_s[2][kk] * w; a3 += e_s[3][kk] * w;
    }
    const int j = kc * 2 + half;
    float* p = part + (size_t)j * 4 * 2048 + n;
    p[0] = a0; p[2048] = a1; p[2 * 2048] = a2; p[3 * 2048] = a3;
}

// ---------------- 2b) ada reduce ----------------
__global__ __launch_bounds__(256) void ada_red_kernel(const float* __restrict__ part,
                                                      const float* __restrict__ bias,
                                                      float* __restrict__ ss) {
    const int idx = blockIdx.x * 256 + threadIdx.x;
    const int b = idx >> 11, n = idx & 2047;
    float acc = bias[n];
    #pragma unroll 8
    for (int j = 0; j < 32; ++j) acc += part[((size_t)j * 4 + b) * 2048 + n];
    ss[b * 2048 + n] = acc;
}

// ---------------- 3) AdaLN ----------------
__global__ __launch_bounds__(256) void adaln_kernel(const float* __restrict__ src,
                                                    const float* __restrict__ ss,
                                                    unsigned short* __restrict__ xb) {
    int r = blockIdx.x;
    int b = r >> 9;
    int t = threadIdx.x;
    float4 v4 = *reinterpret_cast<const float4*>(&src[(size_t)r * DM + t * 4]);
    float v[4] = {v4.x, v4.y, v4.z, v4.w};
    float s = v[0] + v[1] + v[2] + v[3];
    float q = v[0]*v[0] + v[1]*v[1] + v[2]*v[2] + v[3]*v[3];
    #pragma unroll
    for (int off = 32; off > 0; off >>= 1) { s += __shfl_down(s, off); q += __shfl_down(q, off); }
    __shared__ float red[8];
    if ((t & 63) == 0) { red[t >> 6] = s; red[4 + (t >> 6)] = q; }
    __syncthreads();
    s = red[0] + red[1] + red[2] + red[3];
    q = red[4] + red[5] + red[6] + red[7];
    float mean = s * (1.0f / DM);
    float var = q * (1.0f / DM) - mean * mean;
    float rstd = rsqrtf(var + 1e-5f);
    ushort4 o;
    o.x = f2bf_n((v[0]-mean)*rstd*(1.0f+ss[b*2048 + t*4+0]) + ss[b*2048+1024 + t*4+0]);
    o.y = f2bf_n((v[1]-mean)*rstd*(1.0f+ss[b*2048 + t*4+1]) + ss[b*2048+1024 + t*4+1]);
    o.z = f2bf_n((v[2]-mean)*rstd*(1.0f+ss[b*2048 + t*4+2]) + ss[b*2048+1024 + t*4+2]);
    o.w = f2bf_n((v[3]-mean)*rstd*(1.0f+ss[b*2048 + t*4+3]) + ss[b*2048+1024 + t*4+3]);
    *reinterpret_cast<ushort4*>(&xb[(size_t)r * DM + t * 4]) = o;
}

// ---------------- LN2 ----------------
__global__ __launch_bounds__(256) void ln2_kernel(const unsigned short* __restrict__ x,
                                                  const float* __restrict__ g2,
                                                  const float* __restrict__ beta2,
                                                  unsigned short* __restrict__ hout) {
    int r = blockIdx.x;
    int t = threadIdx.x;
    ushort4 s4 = *reinterpret_cast<const ushort4*>(&x[(size_t)r * DM + t * 4]);
    float v[4] = {bf2f(s4.x), bf2f(s4.y), bf2f(s4.z), bf2f(s4.w)};
    float s = v[0] + v[1] + v[2] + v[3];
    float q = v[0]*v[0] + v[1]*v[1] + v[2]*v[2] + v[3]*v[3];
    #pragma unroll
    for (int off = 32; off > 0; off >>= 1) { s += __shfl_down(s, off); q += __shfl_down(q, off); }
    __shared__ float red[8];
    if ((t & 63) == 0) { red[t >> 6] = s; red[4 + (t >> 6)] = q; }
    __syncthreads();
    s = red[0] + red[1] + red[2] + red[3];
    q = red[4] + red[5] + red[6] + red[7];
    float mean = s * (1.0f / DM);
    float var = q * (1.0f / DM) - mean * mean;
    float rstd = rsqrtf(var + 1e-5f);
    ushort4 o;
    o.x = f2bf_n((v[0]-mean)*rstd*g2[t*4+0] + beta2[t*4+0]);
    o.y = f2bf_n((v[1]-mean)*rstd*g2[t*4+1] + beta2[t*4+1]);
    o.z = f2bf_n((v[2]-mean)*rstd*g2[t*4+2] + beta2[t*4+2]);
    o.w = f2bf_n((v[3]-mean)*rstd*g2[t*4+3] + beta2[t*4+3]);
    *reinterpret_cast<ushort4*>(&hout[(size_t)r * DM + t * 4]) = o;
}

// ============ m97-style GEMM: 128xTN tile, global_load_lds + XOR-swizzled source ============
// MODE: 0 ->bf16; 1 +resid->bf16; 2 gelu2->bf16; 3 +bias+resid->f32
// LDS: combined [128+TN rows][64 k] bf16, linear 128B rows.
// Stage: lane l of wave w, inst i -> row cr=w*RPW+i*8+(l>>3), granule slot l&7
//        holds GLOBAL granule (l&7)^(l>>3)  (since cr&7 == l>>3).
// Read: row r, want k-granule g -> slot g^(r&7). XOR cancels -> exact k order.
template<int MODE, int TN>
__global__ __launch_bounds__(256) void gemm_gl(
    const unsigned short* __restrict__ A,
    const unsigned short* __restrict__ Wta, const unsigned short* __restrict__ Wtb,
    const unsigned short* __restrict__ Wtc,
    const float* __restrict__ ba, const float* __restrict__ bbb, const float* __restrict__ bc,
    const unsigned short* __restrict__ resid,
    unsigned short* __restrict__ oa, unsigned short* __restrict__ ob,
    unsigned short* __restrict__ oc,
    float* __restrict__ outF,
    int M, int N, int K, int ldk)
{
    constexpr int CR  = 128 + TN;        // combined staged rows
    constexpr int RPW = CR / 4;          // rows per wave (64 or 48)
    constexpr int NI  = RPW / 8;         // global_load_lds insts per wave
    constexpr int WAVE_N = (TN == 128) ? 2 : 1;
    constexpr int WAVE_M = 4 / WAVE_N;
    constexpr int AM = 128 / (WAVE_M * 16);
    constexpr int AN = TN / (WAVE_N * 16);

    __shared__ unsigned short LDSu[CR * 64];

    // bijective XCD-chunked swizzle, by-fastest
    const int gx = gridDim.x, gy = gridDim.y;
    const int nwg = gx * gy * gridDim.z;
    const int wid = blockIdx.x + gx * (blockIdx.y + gy * blockIdx.z);
    const int aid = (wid & 7) * (nwg >> 3) + (wid >> 3);
    const int plane = gx * gy;
    const int sel = aid / plane;
    const int pid = aid % plane;
    const int by = pid % gy;
    const int bx = pid / gy;

    const unsigned short* Wt = (sel == 0) ? Wta : (sel == 1) ? Wtb : Wtc;
    const float* bias = (sel == 0) ? ba : (sel == 1) ? bbb : bc;
    unsigned short* outB = (sel == 0) ? oa : (sel == 1) ? ob : oc;

    const int t = threadIdx.x;
    const int lane = t & 63;
    const int w = t >> 6;
    const int l15 = lane & 15, l4 = lane >> 4;
    const int wm = w / WAVE_N, wn = w % WAVE_N;
    const int m0 = by * 128, n0 = bx * TN;

    f32x4 acc[AM][AN];
    #pragma unroll
    for (int i = 0; i < AM; ++i)
        #pragma unroll
        for (int j = 0; j < AN; ++j)
            #pragma unroll
            for (int r = 0; r < 4; ++r) acc[i][j][r] = 0.0f;

    // per-lane staging pointers (k0 added in loop)
    const int gg = (lane & 7) ^ (lane >> 3);   // swizzled global granule
    const unsigned short* gp[NI];
    unsigned short* lp[NI];
    #pragma unroll
    for (int i = 0; i < NI; ++i) {
        const int cr = w * RPW + i * 8 + (lane >> 3);
        gp[i] = (cr < 128) ? (A + (size_t)(m0 + cr) * K + gg * 8)
                           : (Wt + (size_t)(n0 + cr - 128) * ldk + gg * 8);
        lp[i] = LDSu + (w * RPW + i * 8) * 64;
    }

    const int NT = K / 64;
    for (int kt = 0; kt < NT; ++kt) {
        const int k0 = kt * 64;
        #pragma unroll
        for (int i = 0; i < NI; ++i) gl_lds16(gp[i] + k0, lp[i]);
        __syncthreads();   // drains vmcnt, data visible

        #pragma unroll
        for (int kk = 0; kk < 2; ++kk) {
            const int slot = ((kk * 4 + l4) ^ (l15 & 7)) * 8;
            bf16x8 af[AM], bfr[AN];
            #pragma unroll
            for (int mt = 0; mt < AM; ++mt) {
                const int row = wm * (AM * 16) + mt * 16 + l15;
                u16x8 tmp = *(const u16x8*)(LDSu + row * 64 + slot);
                af[mt] = __builtin_bit_cast(bf16x8, tmp);
            }
            #pragma unroll
            for (int nt = 0; nt < AN; ++nt) {
                const int row = 128 + wn * (AN * 16) + nt * 16 + l15;
                u16x8 tmp = *(const u16x8*)(LDSu + row * 64 + slot);
                bfr[nt] = __builtin_bit_cast(bf16x8, tmp);
            }
            #pragma unroll
            for (int mt = 0; mt < AM; ++mt)
                #pragma unroll
                for (int nt = 0; nt < AN; ++nt)
                    acc[mt][nt] = __builtin_amdgcn_mfma_f32_16x16x32_bf16(
                        af[mt], bfr[nt], acc[mt][nt], 0, 0, 0);
        }
        if (kt + 1 < NT) __syncthreads();   // protect LDS before next stage
    }

    #pragma unroll
    for (int mt = 0; mt < AM; ++mt) {
        const int mbase = m0 + wm * (AM * 16) + mt * 16 + l4 * 4;
        #pragma unroll
        for (int nt = 0; nt < AN; ++nt) {
            const int n = n0 + wn * (AN * 16) + nt * 16 + l15;
            const float bs = bias[n];
            #pragma unroll
            for (int r = 0; r < 4; ++r) {
                const int m = mbase + r;
                float v = acc[mt][nt][r] + bs;
                if (MODE == 2) v = v / (1.0f + expf(-1.702f * v));
                if (MODE == 1 || MODE == 3) v += bf2f(resid[(size_t)m * N + n]);
                if (MODE == 3) outF[(size_t)m * N + n] = v;
                else           outB[(size_t)m * N + n] = f2bf_n(v);
            }
        }
    }
}

// ---------- MFMA flash attention (round-14/15, verified) ----------
#define QB2 32
#define AKT 64
#define KROW 72
#define VROW 72
#define PROW 72
#define SBPIT 72

__global__ __launch_bounds__(128) void attn_mfma(const unsigned short* __restrict__ qbuf,
                                                 const unsigned short* __restrict__ kbuf,
                                                 const unsigned short* __restrict__ vbuf,
                                                 const float* __restrict__ attb,
                                                 const int* __restrict__ mask,
                                                 unsigned short* __restrict__ ctx) {
    __shared__ unsigned short Ks[AKT * KROW];
    __shared__ unsigned short Vt[DH * VROW];
    __shared__ unsigned short Pb[2 * 16 * PROW];
    __shared__ unsigned short Sb[QB2 * SBPIT];
    const int t = threadIdx.x;
    const int lane = t & 63;
    const int w = t >> 6;
    const int l15 = lane & 15, l4 = lane >> 4;
    const int q0 = blockIdx.x * QB2;
    const int h = blockIdx.y;
    const int b = blockIdx.z;

    bf16x8 qf[2];
    {
        const unsigned short* qrow = qbuf + ((size_t)(b * SEQ + q0 + w * 16 + l15)) * DM + h * DH;
        u16x8 t0 = *(const u16x8*)(qrow + l4 * 8);
        u16x8 t1 = *(const u16x8*)(qrow + 32 + l4 * 8);
        qf[0] = __builtin_bit_cast(bf16x8, t0);
        qf[1] = __builtin_bit_cast(bf16x8, t1);
    }

    float m[4] = {-1e30f, -1e30f, -1e30f, -1e30f};
    float l[4] = {0.0f, 0.0f, 0.0f, 0.0f};
    f32x4 o[4];
    #pragma unroll
    for (int dt = 0; dt < 4; ++dt)
        #pragma unroll
        for (int r = 0; r < 4; ++r) o[dt][r] = 0.0f;

    unsigned short* Pw = Pb + w * 16 * PROW;

    const int kr = t >> 1, c0 = (t & 1) * 32;
    const int kp = t & 31, vg = t >> 5;

    u16x8 rk0, rk1, rk2, rk3, rv0, rv1, rv2, rv3;
    float4 rb[4];
    int4   rm[4];

#define LOADT(KT) {                                                                     \
    const int kbase = (KT) * AKT;                                                       \
    const unsigned short* gk = kbuf + ((size_t)(b * SEQ + kbase + kr)) * DM + h * DH + c0; \
    rk0 = *(const u16x8*)gk;        rk1 = *(const u16x8*)(gk + 8);                      \
    rk2 = *(const u16x8*)(gk + 16); rk3 = *(const u16x8*)(gk + 24);                     \
    const unsigned short* gv = vbuf + ((size_t)(b * SEQ + kbase + 2 * kp)) * DM + h * DH + vg * 8; \
    rv0 = *(const u16x8*)gv;        rv1 = *(const u16x8*)(gv + DM);                     \
    rv2 = *(const u16x8*)(gv + 32); rv3 = *(const u16x8*)(gv + DM + 32);                \
    const float* bp = attb + (((size_t)(b * NH + h)) * SEQ + (q0 + w * 16)) * SEQ + kbase; \
    const int* mp = mask + ((size_t)(b * SEQ) + q0 + w * 16) * SEQ + kbase;             \
    _Pragma("unroll")                                                                   \
    for (int i = 0; i < 4; ++i) {                                                       \
        const int e = lane + i * 64; const int row = e >> 4, cg = e & 15;               \
        rb[i] = *(const float4*)&bp[(size_t)row * SEQ + cg * 4];                        \
        rm[i] = *(const int4*)&mp[(size_t)row * SEQ + cg * 4];                          \
    } }

#define STORET() {                                                                      \
    unsigned short* s = Ks + kr * KROW + c0;                                            \
    *(u16x8*)s = rk0; *(u16x8*)(s + 8) = rk1;                                           \
    *(u16x8*)(s + 16) = rk2; *(u16x8*)(s + 24) = rk3;                                   \
    unsigned int* vt32 = (unsigned int*)Vt;                                             \
    _Pragma("unroll")                                                                   \
    for (int j = 0; j < 8; ++j) {                                                       \
        vt32[(vg * 8 + j) * (VROW / 2) + kp] =                                          \
            (unsigned int)rv0[j] | ((unsigned int)rv1[j] << 16);                        \
        vt32[((vg + 4) * 8 + j) * (VROW / 2) + kp] =                                    \
            (unsigned int)rv2[j] | ((unsigned int)rv3[j] << 16);                        \
    }                                                                                   \
    _Pragma("unroll")                                                                   \
    for (int i = 0; i < 4; ++i) {                                                       \
        const int e = lane + i * 64; const int row = e >> 4, cg = e & 15;               \
        ushort4 cc;                                                                     \
        cc.x = f2bf_n(rm[i].x ? -8e30f : 8.0f * rb[i].x);                               \
        cc.y = f2bf_n(rm[i].y ? -8e30f : 8.0f * rb[i].y);                               \
        cc.z = f2bf_n(rm[i].z ? -8e30f : 8.0f * rb[i].z);                               \
        cc.w = f2bf_n(rm[i].w ? -8e30f : 8.0f * rb[i].w);                               \
        *(ushort4*)&Sb[(w * 16 + row) * SBPIT + cg * 4] = cc;                           \
    } }

    LOADT(0);
    for (int kt = 0; kt < SEQ / AKT; ++kt) {
        __syncthreads();
        STORET();
        __syncthreads();
        if (kt + 1 < SEQ / AKT) LOADT(kt + 1);

        f32x4 acc[4];
        #pragma unroll
        for (int nt = 0; nt < 4; ++nt)
            #pragma unroll
            for (int r = 0; r < 4; ++r)
                acc[nt][r] = bf2f(Sb[(w * 16 + l4 * 4 + r) * SBPIT + nt * 16 + l15]);

        #pragma unroll
        for (int kk = 0; kk < 2; ++kk) {
            #pragma unroll
            for (int nt = 0; nt < 4; ++nt) {
                u16x8 tmp = *(const u16x8*)(Ks + (nt * 16 + l15) * KROW + kk * 32 + l4 * 8);
                acc[nt] = __builtin_amdgcn_mfma_f32_16x16x32_bf16(
                    qf[kk], __builtin_bit_cast(bf16x8, tmp), acc[nt], 0, 0, 0);
            }
        }

        float pm[4] = {-1e30f, -1e30f, -1e30f, -1e30f};
        #pragma unroll
        for (int nt = 0; nt < 4; ++nt) {
            #pragma unroll
            for (int r = 0; r < 4; ++r) {
                const float sv = acc[nt][r] * 0.125f;
                acc[nt][r] = sv;
                pm[r] = fmaxf(pm[r], sv);
            }
        }
        #pragma unroll
        for (int r = 0; r < 4; ++r) {
            #pragma unroll
            for (int off = 1; off < 16; off <<= 1)
                pm[r] = fmaxf(pm[r], __shfl_xor(pm[r], off));
        }
        float al[4], ps[4];
        #pragma unroll
        for (int r = 0; r < 4; ++r) {
            const float mn = fmaxf(m[r], pm[r]);
            al[r] = __expf(m[r] - mn);
            m[r] = mn;
            ps[r] = 0.0f;
        }
        #pragma unroll
        for (int nt = 0; nt < 4; ++nt) {
            #pragma unroll
            for (int r = 0; r < 4; ++r) {
                const float p = __expf(acc[nt][r] - m[r]);
                acc[nt][r] = p;
                ps[r] += p;
            }
        }
        #pragma unroll
        for (int r = 0; r < 4; ++r) {
            #pragma unroll
            for (int off = 1; off < 16; off <<= 1) ps[r] += __shfl_xor(ps[r], off);
            l[r] = l[r] * al[r] + ps[r];
        }
        #pragma unroll
        for (int dt = 0; dt < 4; ++dt)
            #pragma unroll
            for (int r = 0; r < 4; ++r) o[dt][r] *= al[r];

        #pragma unroll
        for (int nt = 0; nt < 4; ++nt)
            #pragma unroll
            for (int r = 0; r < 4; ++r)
                Pw[(l4 * 4 + r) * PROW + nt * 16 + l15] = f2bf_n(acc[nt][r]);

        #pragma unroll
        for (int ks = 0; ks < 2; ++ks) {
            u16x8 pa = *(const u16x8*)(Pw + l15 * PROW + ks * 32 + l4 * 8);
            #pragma unroll
            for (int dt = 0; dt < 4; ++dt) {
                u16x8 vv = *(const u16x8*)(Vt + (dt * 16 + l15) * VROW + ks * 32 + l4 * 8);
                o[dt] = __builtin_amdgcn_mfma_f32_16x16x32_bf16(
                    __builtin_bit_cast(bf16x8, pa), __builtin_bit_cast(bf16x8, vv),
                    o[dt], 0, 0, 0);
            }
        }
    }

    #pragma unroll
    for (int r = 0; r < 4; ++r) {
        const float inv = 1.0f / l[r];
        const size_t row = (size_t)(b * SEQ + q0 + w * 16 + l4 * 4 + r) * DM + h * DH;
        #pragma unroll
        for (int dt = 0; dt < 4; ++dt)
            ctx[row + dt * 16 + l15] = f2bf_n(o[dt][r] * inv);
    }
#undef LOADT
#undef STORET
}

// ---------------- host launch ----------------
extern "C" void kernel_launch(void* const* d_in, const int* in_sizes, int n_in,
                              void* d_out, int out_size, void* d_ws, size_t ws_size,
                              hipStream_t stream) {
    const float* src  = (const float*)d_in[0];
    const int*   mask = (const int*)d_in[1];
    const int*   ts   = (const int*)d_in[2];
    const float* attb = (const float*)d_in[3];
    const float* Wada = (const float*)d_in[4];
    const float* bada = (const float*)d_in[5];
    const float* Wq   = (const float*)d_in[6];
    const float* bq   = (const float*)d_in[7];
    const float* Wk   = (const float*)d_in[8];
    const float* bk   = (const float*)d_in[9];
    const float* Wv   = (const float*)d_in[10];
    const float* bv   = (const float*)d_in[11];
    const float* Wo   = (const float*)d_in[12];
    const float* bo   = (const float*)d_in[13];
    const float* W1   = (const float*)d_in[14];
    const float* b1   = (const float*)d_in[15];
    const float* W2   = (const float*)d_in[16];
    const float* b2   = (const float*)d_in[17];
    const float* g2   = (const float*)d_in[18];
    const float* bt2  = (const float*)d_in[19];
    float* out = (float*)d_out;

    const size_t MB = 1024 * 1024;
    const size_t NEED_FULL = 65536 + 52 * MB;   // proven available (rounds 14/15)
    if (ws_size < NEED_FULL) {
        fill0_kernel<<<(size_t)MROWS * DM / 256, 256, 0, stream>>>(out);
        return;
    }

    char* ws = (char*)d_ws;
    float* semb = (float*)(ws + 4096);
    float* ss   = (float*)(ws + 24576);
    char*  base = ws + 65536;
    unsigned short* slotA = (unsigned short*)(base);
    unsigned short* slotB = (unsigned short*)(base + 4 * MB);
    unsigned short* slotC = (unsigned short*)(base + 8 * MB);
    unsigned short* vb   = (unsigned short*)d_out;
    unsigned short* ctxb = (unsigned short*)((char*)d_out + 4 * MB);
    unsigned short* xb = slotA;
    unsigned short* qb = slotB;
    unsigned short* kb = slotC;
    unsigned short* x2 = slotB;
    unsigned short* hb = slotC;
    float* adap = (float*)slotC;

    unsigned short* Wtq = (unsigned short*)(base + 12 * MB);
    unsigned short* Wtk = Wtq + 1024 * 1024;
    unsigned short* Wtv = Wtk + 1024 * 1024;
    unsigned short* Wto = Wtv + 1024 * 1024;
    unsigned short* Wt1 = Wto + 1024 * 1024;               // [4096][1024]
    unsigned short* Wt2 = Wt1 + (size_t)4096 * 1024;       // [1024][4096]
    unsigned short* midF = (unsigned short*)(base + 36 * MB);  // [2048][4096]

    tconv4_kernel<<<dim3(32, 16, 4), 256, 0, stream>>>(Wq, Wk, Wv, Wo, Wtq, Wtk, Wtv, Wto);
    tconv_kernel<<<dim3(128, 16), 256, 0, stream>>>(W1, Wt1, 1024, 4096);
    tconv_kernel<<<dim3(32, 64), 256, 0, stream>>>(W2, Wt2, 4096, 1024);

    semb_kernel<<<4, 256, 0, stream>>>(ts, semb);
    ada_part_kernel<<<dim3(16, 16), 256, 0, stream>>>(semb, Wada, adap);
    ada_red_kernel<<<32, 256, 0, stream>>>(adap, bada, ss);
    adaln_kernel<<<MROWS, 256, 0, stream>>>(src, ss, xb);

    // QKV fused (grid.z selects weight/bias/out)
    gemm_gl<0, 128><<<dim3(8, 16, 3), 256, 0, stream>>>(
        xb, Wtq, Wtk, Wtv, bq, bk, bv, nullptr, qb, kb, vb, nullptr, MROWS, DM, DM, DM);
    attn_mfma<<<dim3(SEQ / QB2, NH, BATCH), 128, 0, stream>>>(qb, kb, vb, attb, mask, ctxb);
    // x2 = xb + ctx@Wo + bo
    gemm_gl<1, 64><<<dim3(16, 16), 256, 0, stream>>>(
        ctxb, Wto, Wto, Wto, bo, bo, bo, xb, x2, x2, x2, nullptr, MROWS, DM, DM, DM);
    ln2_kernel<<<MROWS, 256, 0, stream>>>(x2, g2, bt2, hb);
    // FFN: mid = gelu2(h@W1+b1); out = mid@W2+b2+x2
    gemm_gl<2, 128><<<dim3(32, 16), 256, 0, stream>>>(
        hb, Wt1, Wt1, Wt1, b1, b1, b1, nullptr, midF, midF, midF, nullptr, MROWS, DFF, DM, DM);
    gemm_gl<3, 64><<<dim3(16, 16), 256, 0, stream>>>(
        midF, Wt2, Wt2, Wt2, b2, b2, b2, x2, nullptr, nullptr, nullptr, out,
        MROWS, DM, DFF, DFF);
}

// Round 17
// 178.259 us; speedup vs baseline: 1.0675x; 1.0675x over previous
//
#include <hip/hip_runtime.h>
#include <math.h>

typedef __bf16 bf16x8 __attribute__((ext_vector_type(8)));
typedef float  f32x4  __attribute__((ext_vector_type(4)));
typedef unsigned short u16x8 __attribute__((ext_vector_type(8)));

__device__ __forceinline__ float bf2f(unsigned short u) {
    return __uint_as_float(((unsigned int)u) << 16);
}
__device__ __forceinline__ unsigned short f2bf_n(float f) {
    return __builtin_bit_cast(unsigned short, (__bf16)f);  // native cvt (RNE)
}
__device__ __forceinline__ void gl_lds16(const unsigned short* g, unsigned short* l) {
    __builtin_amdgcn_global_load_lds(
        (const __attribute__((address_space(1))) unsigned int*)g,
        (__attribute__((address_space(3))) unsigned int*)l, 16, 0, 0);
}

// dims
#define BATCH 4
#define SEQ 512
#define DM 1024
#define NH 16
#define DH 64
#define DFF 4096
#define MROWS (BATCH * SEQ)   // 2048

__global__ __launch_bounds__(256) void fill0_kernel(float* __restrict__ out) {
    out[blockIdx.x * 256 + threadIdx.x] = 0.0f;
}

// ---------------- weight transpose+convert: in[K][N] f32 -> out[N][K] bf16 ----------
__global__ __launch_bounds__(256) void tconv_kernel(const float* __restrict__ in,
                                                    unsigned short* __restrict__ out,
                                                    int K, int N) {
    __shared__ float tile[64][33];
    const int n0 = blockIdx.x * 32, k0 = blockIdx.y * 64;
    const int t = threadIdx.x;
    const int tx = t & 31, ty = t >> 5;
    #pragma unroll
    for (int i = 0; i < 8; ++i)
        tile[ty + i * 8][tx] = in[(size_t)(k0 + ty + i * 8) * N + n0 + tx];
    __syncthreads();
    const int nr = t >> 3;
    const int ks = (t & 7) * 8;
    u16x8 v;
    #pragma unroll
    for (int j = 0; j < 8; ++j) v[j] = f2bf_n(tile[ks + j][nr]);
    *(u16x8*)&out[(size_t)(n0 + nr) * K + k0 + ks] = v;
}

// fused 4x (1024x1024) transpose
__global__ __launch_bounds__(256) void tconv4_kernel(const float* __restrict__ i0,
                                                     const float* __restrict__ i1,
                                                     const float* __restrict__ i2,
                                                     const float* __restrict__ i3,
                                                     unsigned short* __restrict__ o0,
                                                     unsigned short* __restrict__ o1,
                                                     unsigned short* __restrict__ o2,
                                                     unsigned short* __restrict__ o3) {
    const int z = blockIdx.z;
    const float* in = (z == 0) ? i0 : (z == 1) ? i1 : (z == 2) ? i2 : i3;
    unsigned short* out = (z == 0) ? o0 : (z == 1) ? o1 : (z == 2) ? o2 : o3;
    __shared__ float tile[64][33];
    const int n0 = blockIdx.x * 32, k0 = blockIdx.y * 64;
    const int t = threadIdx.x;
    const int tx = t & 31, ty = t >> 5;
    #pragma unroll
    for (int i = 0; i < 8; ++i)
        tile[ty + i * 8][tx] = in[(size_t)(k0 + ty + i * 8) * 1024 + n0 + tx];
    __syncthreads();
    const int nr = t >> 3;
    const int ks = (t & 7) * 8;
    u16x8 v;
    #pragma unroll
    for (int j = 0; j < 8; ++j) v[j] = f2bf_n(tile[ks + j][nr]);
    *(u16x8*)&out[(size_t)(n0 + nr) * 1024 + k0 + ks] = v;
}

// ---------------- 1) sinusoidal emb + silu ----------------
__global__ void semb_kernel(const int* __restrict__ ts, float* __restrict__ semb) {
    int b = blockIdx.x;
    float x = (float)ts[b] * 40.0f;
    for (int j = threadIdx.x; j < 1024; j += 256) {
        int idx = (j < 512) ? j : (j - 512);
        float fr = expf(-9.210340371976184f * (float)idx / 511.0f);
        float e = x * fr;
        float v = (j < 512) ? sinf(e) : cosf(e);
        semb[b * 1024 + j] = v / (1.0f + expf(-v));
    }
}

// ---------------- 2a) ada partials ----------------
__global__ __launch_bounds__(256) void ada_part_kernel(const float* __restrict__ semb,
                                                       const float* __restrict__ W,
                                                       float* __restrict__ part) {
    const int nb = blockIdx.x, kc = blockIdx.y;
    const int t = threadIdx.x;
    __shared__ float e_s[4][64];
    e_s[t >> 6][t & 63] = semb[(t >> 6) * 1024 + kc * 64 + (t & 63)];
    __syncthreads();
    const int n = nb * 128 + (t & 127);
    const int half = t >> 7;
    float a0 = 0.f, a1 = 0.f, a2 = 0.f, a3 = 0.f;
    const int kk0 = half * 32;
    #pragma unroll 8
    for (int kk = kk0; kk < kk0 + 32; ++kk) {
        const float w = W[(size_t)(kc * 64 + kk) * 2048 + n];
        a0 += e_s[0][kk] * w; a1 += e_s[1][kk] * w;
        a2 += e_s[2][kk] * w; a3 += e_s[3][kk] * w;
    }
    const int j = kc * 2 + half;
    float* p = part + (size_t)j * 4 * 2048 + n;
    p[0] = a0; p[2048] = a1; p[2 * 2048] = a2; p[3 * 2048] = a3;
}

// ---------------- 2b) ada reduce ----------------
__global__ __launch_bounds__(256) void ada_red_kernel(const float* __restrict__ part,
                                                      const float* __restrict__ bias,
                                                      float* __restrict__ ss) {
    const int idx = blockIdx.x * 256 + threadIdx.x;
    const int b = idx >> 11, n = idx & 2047;
    float acc = bias[n];
    #pragma unroll 8
    for (int j = 0; j < 32; ++j) acc += part[((size_t)j * 4 + b) * 2048 + n];
    ss[b * 2048 + n] = acc;
}

// ---------------- 3) AdaLN ----------------
__global__ __launch_bounds__(256) void adaln_kernel(const float* __restrict__ src,
                                                    const float* __restrict__ ss,
                                                    unsigned short* __restrict__ xb) {
    int r = blockIdx.x;
    int b = r >> 9;
    int t = threadIdx.x;
    float4 v4 = *reinterpret_cast<const float4*>(&src[(size_t)r * DM + t * 4]);
    float v[4] = {v4.x, v4.y, v4.z, v4.w};
    float s = v[0] + v[1] + v[2] + v[3];
    float q = v[0]*v[0] + v[1]*v[1] + v[2]*v[2] + v[3]*v[3];
    #pragma unroll
    for (int off = 32; off > 0; off >>= 1) { s += __shfl_down(s, off); q += __shfl_down(q, off); }
    __shared__ float red[8];
    if ((t & 63) == 0) { red[t >> 6] = s; red[4 + (t >> 6)] = q; }
    __syncthreads();
    s = red[0] + red[1] + red[2] + red[3];
    q = red[4] + red[5] + red[6] + red[7];
    float mean = s * (1.0f / DM);
    float var = q * (1.0f / DM) - mean * mean;
    float rstd = rsqrtf(var + 1e-5f);
    ushort4 o;
    o.x = f2bf_n((v[0]-mean)*rstd*(1.0f+ss[b*2048 + t*4+0]) + ss[b*2048+1024 + t*4+0]);
    o.y = f2bf_n((v[1]-mean)*rstd*(1.0f+ss[b*2048 + t*4+1]) + ss[b*2048+1024 + t*4+1]);
    o.z = f2bf_n((v[2]-mean)*rstd*(1.0f+ss[b*2048 + t*4+2]) + ss[b*2048+1024 + t*4+2]);
    o.w = f2bf_n((v[3]-mean)*rstd*(1.0f+ss[b*2048 + t*4+3]) + ss[b*2048+1024 + t*4+3]);
    *reinterpret_cast<ushort4*>(&xb[(size_t)r * DM + t * 4]) = o;
}

// ---------------- LN2 ----------------
__global__ __launch_bounds__(256) void ln2_kernel(const unsigned short* __restrict__ x,
                                                  const float* __restrict__ g2,
                                                  const float* __restrict__ beta2,
                                                  unsigned short* __restrict__ hout) {
    int r = blockIdx.x;
    int t = threadIdx.x;
    ushort4 s4 = *reinterpret_cast<const ushort4*>(&x[(size_t)r * DM + t * 4]);
    float v[4] = {bf2f(s4.x), bf2f(s4.y), bf2f(s4.z), bf2f(s4.w)};
    float s = v[0] + v[1] + v[2] + v[3];
    float q = v[0]*v[0] + v[1]*v[1] + v[2]*v[2] + v[3]*v[3];
    #pragma unroll
    for (int off = 32; off > 0; off >>= 1) { s += __shfl_down(s, off); q += __shfl_down(q, off); }
    __shared__ float red[8];
    if ((t & 63) == 0) { red[t >> 6] = s; red[4 + (t >> 6)] = q; }
    __syncthreads();
    s = red[0] + red[1] + red[2] + red[3];
    q = red[4] + red[5] + red[6] + red[7];
    float mean = s * (1.0f / DM);
    float var = q * (1.0f / DM) - mean * mean;
    float rstd = rsqrtf(var + 1e-5f);
    ushort4 o;
    o.x = f2bf_n((v[0]-mean)*rstd*g2[t*4+0] + beta2[t*4+0]);
    o.y = f2bf_n((v[1]-mean)*rstd*g2[t*4+1] + beta2[t*4+1]);
    o.z = f2bf_n((v[2]-mean)*rstd*g2[t*4+2] + beta2[t*4+2]);
    o.w = f2bf_n((v[3]-mean)*rstd*g2[t*4+3] + beta2[t*4+3]);
    *reinterpret_cast<ushort4*>(&hout[(size_t)r * DM + t * 4]) = o;
}

// ---------------- FFN merge: out = P0 + P1 + b2 + x2 ----------------
__global__ __launch_bounds__(256) void merge_kernel(const unsigned short* __restrict__ P0,
                                                    const unsigned short* __restrict__ P1,
                                                    const float* __restrict__ b2,
                                                    const unsigned short* __restrict__ x2,
                                                    float* __restrict__ out) {
    const size_t i4 = ((size_t)blockIdx.x * 256 + threadIdx.x) * 4;
    const int c = (int)(i4 & 1023);
    ushort4 p0 = *(const ushort4*)&P0[i4];
    ushort4 p1 = *(const ushort4*)&P1[i4];
    ushort4 xx = *(const ushort4*)&x2[i4];
    float4 bb = *(const float4*)&b2[c];
    float4 o;
    o.x = bf2f(p0.x) + bf2f(p1.x) + bb.x + bf2f(xx.x);
    o.y = bf2f(p0.y) + bf2f(p1.y) + bb.y + bf2f(xx.y);
    o.z = bf2f(p0.z) + bf2f(p1.z) + bb.z + bf2f(xx.z);
    o.w = bf2f(p0.w) + bf2f(p1.w) + bb.w + bf2f(xx.w);
    *(float4*)&out[i4] = o;
}

// ============ m97-style GEMM: 128xTN tile, global_load_lds + XOR-swizzled source ============
// MODE: 0 ->bf16+bias; 1 +resid->bf16; 2 gelu2->bf16; 3 +bias+resid->f32; 5 ->bf16 no bias
// SELMODE: 0 = grid.z selects weight/bias/out triple; 1 = grid.z selects K-half + partial out
template<int MODE, int TN, int SELMODE>
__global__ __launch_bounds__(256) void gemm_gl(
    const unsigned short* __restrict__ A,
    const unsigned short* __restrict__ Wta, const unsigned short* __restrict__ Wtb,
    const unsigned short* __restrict__ Wtc,
    const float* __restrict__ ba, const float* __restrict__ bbb, const float* __restrict__ bc,
    const unsigned short* __restrict__ resid,
    unsigned short* __restrict__ oa, unsigned short* __restrict__ ob,
    unsigned short* __restrict__ oc,
    float* __restrict__ outF,
    int M, int N, int K, int lda, int ldk)
{
    constexpr int CR  = 128 + TN;
    constexpr int RPW = CR / 4;
    constexpr int NI  = RPW / 8;
    constexpr int WAVE_N = (TN == 128) ? 2 : 1;
    constexpr int WAVE_M = 4 / WAVE_N;
    constexpr int AM = 128 / (WAVE_M * 16);
    constexpr int AN = TN / (WAVE_N * 16);

    __shared__ unsigned short LDSu[CR * 64];

    const int gx = gridDim.x, gy = gridDim.y;
    const int nwg = gx * gy * gridDim.z;
    const int wid = blockIdx.x + gx * (blockIdx.y + gy * blockIdx.z);
    const int aid = (wid & 7) * (nwg >> 3) + (wid >> 3);
    const int plane = gx * gy;
    const int sel = aid / plane;
    const int pid = aid % plane;
    const int by = pid % gy;
    const int bx = pid / gy;

    const unsigned short* Wt;
    const float* bias;
    unsigned short* outB;
    int koff;
    if (SELMODE == 0) {
        Wt = (sel == 0) ? Wta : (sel == 1) ? Wtb : Wtc;
        bias = (sel == 0) ? ba : (sel == 1) ? bbb : bc;
        outB = (sel == 0) ? oa : (sel == 1) ? ob : oc;
        koff = 0;
    } else {
        Wt = Wta; bias = ba;
        outB = (sel == 0) ? oa : ob;
        koff = sel * K;
    }

    const int t = threadIdx.x;
    const int lane = t & 63;
    const int w = t >> 6;
    const int l15 = lane & 15, l4 = lane >> 4;
    const int wm = w / WAVE_N, wn = w % WAVE_N;
    const int m0 = by * 128, n0 = bx * TN;

    f32x4 acc[AM][AN];
    #pragma unroll
    for (int i = 0; i < AM; ++i)
        #pragma unroll
        for (int j = 0; j < AN; ++j)
            #pragma unroll
            for (int r = 0; r < 4; ++r) acc[i][j][r] = 0.0f;

    const int gg = (lane & 7) ^ (lane >> 3);
    const unsigned short* gp[NI];
    unsigned short* lp[NI];
    #pragma unroll
    for (int i = 0; i < NI; ++i) {
        const int cr = w * RPW + i * 8 + (lane >> 3);
        gp[i] = (cr < 128) ? (A + (size_t)(m0 + cr) * lda + koff + gg * 8)
                           : (Wt + (size_t)(n0 + cr - 128) * ldk + koff + gg * 8);
        lp[i] = LDSu + (w * RPW + i * 8) * 64;
    }

    const int NT = K / 64;
    for (int kt = 0; kt < NT; ++kt) {
        const int k0 = kt * 64;
        #pragma unroll
        for (int i = 0; i < NI; ++i) gl_lds16(gp[i] + k0, lp[i]);
        __syncthreads();

        #pragma unroll
        for (int kk = 0; kk < 2; ++kk) {
            const int slot = ((kk * 4 + l4) ^ (l15 & 7)) * 8;
            bf16x8 af[AM], bfr[AN];
            #pragma unroll
            for (int mt = 0; mt < AM; ++mt) {
                const int row = wm * (AM * 16) + mt * 16 + l15;
                u16x8 tmp = *(const u16x8*)(LDSu + row * 64 + slot);
                af[mt] = __builtin_bit_cast(bf16x8, tmp);
            }
            #pragma unroll
            for (int nt = 0; nt < AN; ++nt) {
                const int row = 128 + wn * (AN * 16) + nt * 16 + l15;
                u16x8 tmp = *(const u16x8*)(LDSu + row * 64 + slot);
                bfr[nt] = __builtin_bit_cast(bf16x8, tmp);
            }
            #pragma unroll
            for (int mt = 0; mt < AM; ++mt)
                #pragma unroll
                for (int nt = 0; nt < AN; ++nt)
                    acc[mt][nt] = __builtin_amdgcn_mfma_f32_16x16x32_bf16(
                        af[mt], bfr[nt], acc[mt][nt], 0, 0, 0);
        }
        if (kt + 1 < NT) __syncthreads();
    }

    #pragma unroll
    for (int mt = 0; mt < AM; ++mt) {
        const int mbase = m0 + wm * (AM * 16) + mt * 16 + l4 * 4;
        #pragma unroll
        for (int nt = 0; nt < AN; ++nt) {
            const int n = n0 + wn * (AN * 16) + nt * 16 + l15;
            const float bs = (MODE == 5) ? 0.0f : bias[n];
            #pragma unroll
            for (int r = 0; r < 4; ++r) {
                const int m = mbase + r;
                float v = acc[mt][nt][r] + bs;
                if (MODE == 2) v = v / (1.0f + expf(-1.702f * v));
                if (MODE == 1 || MODE == 3) v += bf2f(resid[(size_t)m * N + n]);
                if (MODE == 3) outF[(size_t)m * N + n] = v;
                else           outB[(size_t)m * N + n] = f2bf_n(v);
            }
        }
    }
}

// ---------- MFMA flash attention (verified) ----------
#define QB2 32
#define AKT 64
#define KROW 72
#define VROW 72
#define PROW 72
#define SBPIT 72

__global__ __launch_bounds__(128) void attn_mfma(const unsigned short* __restrict__ qbuf,
                                                 const unsigned short* __restrict__ kbuf,
                                                 const unsigned short* __restrict__ vbuf,
                                                 const float* __restrict__ attb,
                                                 const int* __restrict__ mask,
                                                 unsigned short* __restrict__ ctx) {
    __shared__ unsigned short Ks[AKT * KROW];
    __shared__ unsigned short Vt[DH * VROW];
    __shared__ unsigned short Pb[2 * 16 * PROW];
    __shared__ unsigned short Sb[QB2 * SBPIT];
    const int t = threadIdx.x;
    const int lane = t & 63;
    const int w = t >> 6;
    const int l15 = lane & 15, l4 = lane >> 4;
    const int q0 = blockIdx.x * QB2;
    const int h = blockIdx.y;
    const int b = blockIdx.z;

    bf16x8 qf[2];
    {
        const unsigned short* qrow = qbuf + ((size_t)(b * SEQ + q0 + w * 16 + l15)) * DM + h * DH;
        u16x8 t0 = *(const u16x8*)(qrow + l4 * 8);
        u16x8 t1 = *(const u16x8*)(qrow + 32 + l4 * 8);
        qf[0] = __builtin_bit_cast(bf16x8, t0);
        qf[1] = __builtin_bit_cast(bf16x8, t1);
    }

    float m[4] = {-1e30f, -1e30f, -1e30f, -1e30f};
    float l[4] = {0.0f, 0.0f, 0.0f, 0.0f};
    f32x4 o[4];
    #pragma unroll
    for (int dt = 0; dt < 4; ++dt)
        #pragma unroll
        for (int r = 0; r < 4; ++r) o[dt][r] = 0.0f;

    unsigned short* Pw = Pb + w * 16 * PROW;

    const int kr = t >> 1, c0 = (t & 1) * 32;
    const int kp = t & 31, vg = t >> 5;

    u16x8 rk0, rk1, rk2, rk3, rv0, rv1, rv2, rv3;
    float4 rb[4];
    int4   rm[4];

#define LOADT(KT) {                                                                     \
    const int kbase = (KT) * AKT;                                                       \
    const unsigned short* gk = kbuf + ((size_t)(b * SEQ + kbase + kr)) * DM + h * DH + c0; \
    rk0 = *(const u16x8*)gk;        rk1 = *(const u16x8*)(gk + 8);                      \
    rk2 = *(const u16x8*)(gk + 16); rk3 = *(const u16x8*)(gk + 24);                     \
    const unsigned short* gv = vbuf + ((size_t)(b * SEQ + kbase + 2 * kp)) * DM + h * DH + vg * 8; \
    rv0 = *(const u16x8*)gv;        rv1 = *(const u16x8*)(gv + DM);                     \
    rv2 = *(const u16x8*)(gv + 32); rv3 = *(const u16x8*)(gv + DM + 32);                \
    const float* bp = attb + (((size_t)(b * NH + h)) * SEQ + (q0 + w * 16)) * SEQ + kbase; \
    const int* mp = mask + ((size_t)(b * SEQ) + q0 + w * 16) * SEQ + kbase;             \
    _Pragma("unroll")                                                                   \
    for (int i = 0; i < 4; ++i) {                                                       \
        const int e = lane + i * 64; const int row = e >> 4, cg = e & 15;               \
        rb[i] = *(const float4*)&bp[(size_t)row * SEQ + cg * 4];                        \
        rm[i] = *(const int4*)&mp[(size_t)row * SEQ + cg * 4];                          \
    } }

#define STORET() {                                                                      \
    unsigned short* s = Ks + kr * KROW + c0;                                            \
    *(u16x8*)s = rk0; *(u16x8*)(s + 8) = rk1;                                           \
    *(u16x8*)(s + 16) = rk2; *(u16x8*)(s + 24) = rk3;                                   \
    unsigned int* vt32 = (unsigned int*)Vt;                                             \
    _Pragma("unroll")                                                                   \
    for (int j = 0; j < 8; ++j) {                                                       \
        vt32[(vg * 8 + j) * (VROW / 2) + kp] =                                          \
            (unsigned int)rv0[j] | ((unsigned int)rv1[j] << 16);                        \
        vt32[((vg + 4) * 8 + j) * (VROW / 2) + kp] =                                    \
            (unsigned int)rv2[j] | ((unsigned int)rv3[j] << 16);                        \
    }                                                                                   \
    _Pragma("unroll")                                                                   \
    for (int i = 0; i < 4; ++i) {                                                       \
        const int e = lane + i * 64; const int row = e >> 4, cg = e & 15;               \
        ushort4 cc;                                                                     \
        cc.x = f2bf_n(rm[i].x ? -8e30f : 8.0f * rb[i].x);                               \
        cc.y = f2bf_n(rm[i].y ? -8e30f : 8.0f * rb[i].y);                               \
        cc.z = f2bf_n(rm[i].z ? -8e30f : 8.0f * rb[i].z);                               \
        cc.w = f2bf_n(rm[i].w ? -8e30f : 8.0f * rb[i].w);                               \
        *(ushort4*)&Sb[(w * 16 + row) * SBPIT + cg * 4] = cc;                           \
    } }

    LOADT(0);
    for (int kt = 0; kt < SEQ / AKT; ++kt) {
        __syncthreads();
        STORET();
        __syncthreads();
        if (kt + 1 < SEQ / AKT) LOADT(kt + 1);

        f32x4 acc[4];
        #pragma unroll
        for (int nt = 0; nt < 4; ++nt)
            #pragma unroll
            for (int r = 0; r < 4; ++r)
                acc[nt][r] = bf2f(Sb[(w * 16 + l4 * 4 + r) * SBPIT + nt * 16 + l15]);

        #pragma unroll
        for (int kk = 0; kk < 2; ++kk) {
            #pragma unroll
            for (int nt = 0; nt < 4; ++nt) {
                u16x8 tmp = *(const u16x8*)(Ks + (nt * 16 + l15) * KROW + kk * 32 + l4 * 8);
                acc[nt] = __builtin_amdgcn_mfma_f32_16x16x32_bf16(
                    qf[kk], __builtin_bit_cast(bf16x8, tmp), acc[nt], 0, 0, 0);
            }
        }

        float pm[4] = {-1e30f, -1e30f, -1e30f, -1e30f};
        #pragma unroll
        for (int nt = 0; nt < 4; ++nt) {
            #pragma unroll
            for (int r = 0; r < 4; ++r) {
                const float sv = acc[nt][r] * 0.125f;
                acc[nt][r] = sv;
                pm[r] = fmaxf(pm[r], sv);
            }
        }
        #pragma unroll
        for (int r = 0; r < 4; ++r) {
            #pragma unroll
            for (int off = 1; off < 16; off <<= 1)
                pm[r] = fmaxf(pm[r], __shfl_xor(pm[r], off));
        }
        float al[4], ps[4];
        #pragma unroll
        for (int r = 0; r < 4; ++r) {
            const float mn = fmaxf(m[r], pm[r]);
            al[r] = __expf(m[r] - mn);
            m[r] = mn;
            ps[r] = 0.0f;
        }
        #pragma unroll
        for (int nt = 0; nt < 4; ++nt) {
            #pragma unroll
            for (int r = 0; r < 4; ++r) {
                const float p = __expf(acc[nt][r] - m[r]);
                acc[nt][r] = p;
                ps[r] += p;
            }
        }
        #pragma unroll
        for (int r = 0; r < 4; ++r) {
            #pragma unroll
            for (int off = 1; off < 16; off <<= 1) ps[r] += __shfl_xor(ps[r], off);
            l[r] = l[r] * al[r] + ps[r];
        }
        #pragma unroll
        for (int dt = 0; dt < 4; ++dt)
            #pragma unroll
            for (int r = 0; r < 4; ++r) o[dt][r] *= al[r];

        #pragma unroll
        for (int nt = 0; nt < 4; ++nt)
            #pragma unroll
            for (int r = 0; r < 4; ++r)
                Pw[(l4 * 4 + r) * PROW + nt * 16 + l15] = f2bf_n(acc[nt][r]);

        #pragma unroll
        for (int ks = 0; ks < 2; ++ks) {
            u16x8 pa = *(const u16x8*)(Pw + l15 * PROW + ks * 32 + l4 * 8);
            #pragma unroll
            for (int dt = 0; dt < 4; ++dt) {
                u16x8 vv = *(const u16x8*)(Vt + (dt * 16 + l15) * VROW + ks * 32 + l4 * 8);
                o[dt] = __builtin_amdgcn_mfma_f32_16x16x32_bf16(
                    __builtin_bit_cast(bf16x8, pa), __builtin_bit_cast(bf16x8, vv),
                    o[dt], 0, 0, 0);
            }
        }
    }

    #pragma unroll
    for (int r = 0; r < 4; ++r) {
        const float inv = 1.0f / l[r];
        const size_t row = (size_t)(b * SEQ + q0 + w * 16 + l4 * 4 + r) * DM + h * DH;
        #pragma unroll
        for (int dt = 0; dt < 4; ++dt)
            ctx[row + dt * 16 + l15] = f2bf_n(o[dt][r] * inv);
    }
#undef LOADT
#undef STORET
}

// ---------------- host launch ----------------
extern "C" void kernel_launch(void* const* d_in, const int* in_sizes, int n_in,
                              void* d_out, int out_size, void* d_ws, size_t ws_size,
                              hipStream_t stream) {
    const float* src  = (const float*)d_in[0];
    const int*   mask = (const int*)d_in[1];
    const int*   ts   = (const int*)d_in[2];
    const float* attb = (const float*)d_in[3];
    const float* Wada = (const float*)d_in[4];
    const float* bada = (const float*)d_in[5];
    const float* Wq   = (const float*)d_in[6];
    const float* bq   = (const float*)d_in[7];
    const float* Wk   = (const float*)d_in[8];
    const float* bk   = (const float*)d_in[9];
    const float* Wv   = (const float*)d_in[10];
    const float* bv   = (const float*)d_in[11];
    const float* Wo   = (const float*)d_in[12];
    const float* bo   = (const float*)d_in[13];
    const float* W1   = (const float*)d_in[14];
    const float* b1   = (const float*)d_in[15];
    const float* W2   = (const float*)d_in[16];
    const float* b2   = (const float*)d_in[17];
    const float* g2   = (const float*)d_in[18];
    const float* bt2  = (const float*)d_in[19];
    float* out = (float*)d_out;

    const size_t MB = 1024 * 1024;
    const size_t NEED_FULL = 65536 + 52 * MB;   // proven available
    if (ws_size < NEED_FULL) {
        fill0_kernel<<<(size_t)MROWS * DM / 256, 256, 0, stream>>>(out);
        return;
    }

    char* ws = (char*)d_ws;
    float* semb = (float*)(ws + 4096);
    float* ss   = (float*)(ws + 24576);
    char*  base = ws + 65536;
    unsigned short* slotA = (unsigned short*)(base);
    unsigned short* slotB = (unsigned short*)(base + 4 * MB);
    unsigned short* slotC = (unsigned short*)(base + 8 * MB);
    unsigned short* vb   = (unsigned short*)d_out;
    unsigned short* ctxb = (unsigned short*)((char*)d_out + 4 * MB);
    unsigned short* xb = slotA;
    unsigned short* qb = slotB;
    unsigned short* kb = slotC;
    unsigned short* x2 = slotB;
    unsigned short* hb = slotC;
    unsigned short* P0 = slotA;   // W2 partial 0 (xb dead after Wo)
    unsigned short* P1 = slotC;   // W2 partial 1 (hb dead after W1)
    float* adap = (float*)slotC;

    unsigned short* Wtq = (unsigned short*)(base + 12 * MB);
    unsigned short* Wtk = Wtq + 1024 * 1024;
    unsigned short* Wtv = Wtk + 1024 * 1024;
    unsigned short* Wto = Wtv + 1024 * 1024;
    unsigned short* Wt1 = Wto + 1024 * 1024;               // [4096][1024]
    unsigned short* Wt2 = Wt1 + (size_t)4096 * 1024;       // [1024][4096]
    unsigned short* midF = (unsigned short*)(base + 36 * MB);  // [2048][4096]

    tconv4_kernel<<<dim3(32, 16, 4), 256, 0, stream>>>(Wq, Wk, Wv, Wo, Wtq, Wtk, Wtv, Wto);
    tconv_kernel<<<dim3(128, 16), 256, 0, stream>>>(W1, Wt1, 1024, 4096);
    tconv_kernel<<<dim3(32, 64), 256, 0, stream>>>(W2, Wt2, 4096, 1024);

    semb_kernel<<<4, 256, 0, stream>>>(ts, semb);
    ada_part_kernel<<<dim3(16, 16), 256, 0, stream>>>(semb, Wada, adap);
    ada_red_kernel<<<32, 256, 0, stream>>>(adap, bada, ss);
    adaln_kernel<<<MROWS, 256, 0, stream>>>(src, ss, xb);

    // QKV fused (grid.z selects weight/bias/out)
    gemm_gl<0, 128, 0><<<dim3(8, 16, 3), 256, 0, stream>>>(
        xb, Wtq, Wtk, Wtv, bq, bk, bv, nullptr, qb, kb, vb, nullptr,
        MROWS, DM, DM, DM, DM);
    attn_mfma<<<dim3(SEQ / QB2, NH, BATCH), 128, 0, stream>>>(qb, kb, vb, attb, mask, ctxb);
    // x2 = xb + ctx@Wo + bo
    gemm_gl<1, 64, 0><<<dim3(16, 16), 256, 0, stream>>>(
        ctxb, Wto, Wto, Wto, bo, bo, bo, xb, x2, x2, x2, nullptr,
        MROWS, DM, DM, DM, DM);
    ln2_kernel<<<MROWS, 256, 0, stream>>>(x2, g2, bt2, hb);
    // FFN: mid = gelu2(h@W1+b1)
    gemm_gl<2, 128, 0><<<dim3(32, 16), 256, 0, stream>>>(
        hb, Wt1, Wt1, Wt1, b1, b1, b1, nullptr, midF, midF, midF, nullptr,
        MROWS, DFF, DM, DM, DM);
    // W2 K-split: z=0 -> P0 (K 0..2047), z=1 -> P1 (K 2048..4095), bf16 partials
    gemm_gl<5, 128, 1><<<dim3(8, 16, 2), 256, 0, stream>>>(
        midF, Wt2, Wt2, Wt2, b2, b2, b2, nullptr, P0, P1, nullptr, nullptr,
        MROWS, DM, 2048, DFF, DFF);
    // out = P0 + P1 + b2 + x2
    merge_kernel<<<(size_t)MROWS * DM / 1024, 256, 0, stream>>>(P0, P1, b2, x2, out);
}

// Round 18
// 156.931 us; speedup vs baseline: 1.2125x; 1.1359x over previous
//
#include <hip/hip_runtime.h>
#include <math.h>

typedef __bf16 bf16x8 __attribute__((ext_vector_type(8)));
typedef float  f32x4  __attribute__((ext_vector_type(4)));
typedef unsigned short u16x8 __attribute__((ext_vector_type(8)));

__device__ __forceinline__ float bf2f(unsigned short u) {
    return __uint_as_float(((unsigned int)u) << 16);
}
__device__ __forceinline__ unsigned short f2bf_n(float f) {
    return __builtin_bit_cast(unsigned short, (__bf16)f);  // native cvt (RNE)
}
__device__ __forceinline__ void gl_lds16(const unsigned short* g, unsigned short* l) {
    __builtin_amdgcn_global_load_lds(
        (const __attribute__((address_space(1))) unsigned int*)g,
        (__attribute__((address_space(3))) unsigned int*)l, 16, 0, 0);
}

// dims
#define BATCH 4
#define SEQ 512
#define DM 1024
#define NH 16
#define DH 64
#define DFF 4096
#define MROWS (BATCH * SEQ)   // 2048

__global__ __launch_bounds__(256) void fill0_kernel(float* __restrict__ out) {
    out[blockIdx.x * 256 + threadIdx.x] = 0.0f;
}

// ---------------- weight transpose+convert: in[K][N] f32 -> out[N][K] bf16 ----------
__global__ __launch_bounds__(256) void tconv_kernel(const float* __restrict__ in,
                                                    unsigned short* __restrict__ out,
                                                    int K, int N) {
    __shared__ float tile[64][33];
    const int n0 = blockIdx.x * 32, k0 = blockIdx.y * 64;
    const int t = threadIdx.x;
    const int tx = t & 31, ty = t >> 5;
    #pragma unroll
    for (int i = 0; i < 8; ++i)
        tile[ty + i * 8][tx] = in[(size_t)(k0 + ty + i * 8) * N + n0 + tx];
    __syncthreads();
    const int nr = t >> 3;
    const int ks = (t & 7) * 8;
    u16x8 v;
    #pragma unroll
    for (int j = 0; j < 8; ++j) v[j] = f2bf_n(tile[ks + j][nr]);
    *(u16x8*)&out[(size_t)(n0 + nr) * K + k0 + ks] = v;
}

// fused 4x (1024x1024) transpose
__global__ __launch_bounds__(256) void tconv4_kernel(const float* __restrict__ i0,
                                                     const float* __restrict__ i1,
                                                     const float* __restrict__ i2,
                                                     const float* __restrict__ i3,
                                                     unsigned short* __restrict__ o0,
                                                     unsigned short* __restrict__ o1,
                                                     unsigned short* __restrict__ o2,
                                                     unsigned short* __restrict__ o3) {
    const int z = blockIdx.z;
    const float* in = (z == 0) ? i0 : (z == 1) ? i1 : (z == 2) ? i2 : i3;
    unsigned short* out = (z == 0) ? o0 : (z == 1) ? o1 : (z == 2) ? o2 : o3;
    __shared__ float tile[64][33];
    const int n0 = blockIdx.x * 32, k0 = blockIdx.y * 64;
    const int t = threadIdx.x;
    const int tx = t & 31, ty = t >> 5;
    #pragma unroll
    for (int i = 0; i < 8; ++i)
        tile[ty + i * 8][tx] = in[(size_t)(k0 + ty + i * 8) * 1024 + n0 + tx];
    __syncthreads();
    const int nr = t >> 3;
    const int ks = (t & 7) * 8;
    u16x8 v;
    #pragma unroll
    for (int j = 0; j < 8; ++j) v[j] = f2bf_n(tile[ks + j][nr]);
    *(u16x8*)&out[(size_t)(n0 + nr) * 1024 + k0 + ks] = v;
}

// ---------------- 1) sinusoidal emb + silu ----------------
__global__ void semb_kernel(const int* __restrict__ ts, float* __restrict__ semb) {
    int b = blockIdx.x;
    float x = (float)ts[b] * 40.0f;
    for (int j = threadIdx.x; j < 1024; j += 256) {
        int idx = (j < 512) ? j : (j - 512);
        float fr = expf(-9.210340371976184f * (float)idx / 511.0f);
        float e = x * fr;
        float v = (j < 512) ? sinf(e) : cosf(e);
        semb[b * 1024 + j] = v / (1.0f + expf(-v));
    }
}

// ---------------- 2a) ada partials ----------------
__global__ __launch_bounds__(256) void ada_part_kernel(const float* __restrict__ semb,
                                                       const float* __restrict__ W,
                                                       float* __restrict__ part) {
    const int nb = blockIdx.x, kc = blockIdx.y;
    const int t = threadIdx.x;
    __shared__ float e_s[4][64];
    e_s[t >> 6][t & 63] = semb[(t >> 6) * 1024 + kc * 64 + (t & 63)];
    __syncthreads();
    const int n = nb * 128 + (t & 127);
    const int half = t >> 7;
    float a0 = 0.f, a1 = 0.f, a2 = 0.f, a3 = 0.f;
    const int kk0 = half * 32;
    #pragma unroll 8
    for (int kk = kk0; kk < kk0 + 32; ++kk) {
        const float w = W[(size_t)(kc * 64 + kk) * 2048 + n];
        a0 += e_s[0][kk] * w; a1 += e_s[1][kk] * w;
        a2 += e_s[2][kk] * w; a3 += e_s[3][kk] * w;
    }
    const int j = kc * 2 + half;
    float* p = part + (size_t)j * 4 * 2048 + n;
    p[0] = a0; p[2048] = a1; p[2 * 2048] = a2; p[3 * 2048] = a3;
}

// ---------------- 2b) ada reduce ----------------
__global__ __launch_bounds__(256) void ada_red_kernel(const float* __restrict__ part,
                                                      const float* __restrict__ bias,
                                                      float* __restrict__ ss) {
    const int idx = blockIdx.x * 256 + threadIdx.x;
    const int b = idx >> 11, n = idx & 2047;
    float acc = bias[n];
    #pragma unroll 8
    for (int j = 0; j < 32; ++j) acc += part[((size_t)j * 4 + b) * 2048 + n];
    ss[b * 2048 + n] = acc;
}

// ---------------- 3) AdaLN ----------------
__global__ __launch_bounds__(256) void adaln_kernel(const float* __restrict__ src,
                                                    const float* __restrict__ ss,
                                                    unsigned short* __restrict__ xb) {
    int r = blockIdx.x;
    int b = r >> 9;
    int t = threadIdx.x;
    float4 v4 = *reinterpret_cast<const float4*>(&src[(size_t)r * DM + t * 4]);
    float v[4] = {v4.x, v4.y, v4.z, v4.w};
    float s = v[0] + v[1] + v[2] + v[3];
    float q = v[0]*v[0] + v[1]*v[1] + v[2]*v[2] + v[3]*v[3];
    #pragma unroll
    for (int off = 32; off > 0; off >>= 1) { s += __shfl_down(s, off); q += __shfl_down(q, off); }
    __shared__ float red[8];
    if ((t & 63) == 0) { red[t >> 6] = s; red[4 + (t >> 6)] = q; }
    __syncthreads();
    s = red[0] + red[1] + red[2] + red[3];
    q = red[4] + red[5] + red[6] + red[7];
    float mean = s * (1.0f / DM);
    float var = q * (1.0f / DM) - mean * mean;
    float rstd = rsqrtf(var + 1e-5f);
    ushort4 o;
    o.x = f2bf_n((v[0]-mean)*rstd*(1.0f+ss[b*2048 + t*4+0]) + ss[b*2048+1024 + t*4+0]);
    o.y = f2bf_n((v[1]-mean)*rstd*(1.0f+ss[b*2048 + t*4+1]) + ss[b*2048+1024 + t*4+1]);
    o.z = f2bf_n((v[2]-mean)*rstd*(1.0f+ss[b*2048 + t*4+2]) + ss[b*2048+1024 + t*4+2]);
    o.w = f2bf_n((v[3]-mean)*rstd*(1.0f+ss[b*2048 + t*4+3]) + ss[b*2048+1024 + t*4+3]);
    *reinterpret_cast<ushort4*>(&xb[(size_t)r * DM + t * 4]) = o;
}

// ---------------- LN2 ----------------
__global__ __launch_bounds__(256) void ln2_kernel(const unsigned short* __restrict__ x,
                                                  const float* __restrict__ g2,
                                                  const float* __restrict__ beta2,
                                                  unsigned short* __restrict__ hout) {
    int r = blockIdx.x;
    int t = threadIdx.x;
    ushort4 s4 = *reinterpret_cast<const ushort4*>(&x[(size_t)r * DM + t * 4]);
    float v[4] = {bf2f(s4.x), bf2f(s4.y), bf2f(s4.z), bf2f(s4.w)};
    float s = v[0] + v[1] + v[2] + v[3];
    float q = v[0]*v[0] + v[1]*v[1] + v[2]*v[2] + v[3]*v[3];
    #pragma unroll
    for (int off = 32; off > 0; off >>= 1) { s += __shfl_down(s, off); q += __shfl_down(q, off); }
    __shared__ float red[8];
    if ((t & 63) == 0) { red[t >> 6] = s; red[4 + (t >> 6)] = q; }
    __syncthreads();
    s = red[0] + red[1] + red[2] + red[3];
    q = red[4] + red[5] + red[6] + red[7];
    float mean = s * (1.0f / DM);
    float var = q * (1.0f / DM) - mean * mean;
    float rstd = rsqrtf(var + 1e-5f);
    ushort4 o;
    o.x = f2bf_n((v[0]-mean)*rstd*g2[t*4+0] + beta2[t*4+0]);
    o.y = f2bf_n((v[1]-mean)*rstd*g2[t*4+1] + beta2[t*4+1]);
    o.z = f2bf_n((v[2]-mean)*rstd*g2[t*4+2] + beta2[t*4+2]);
    o.w = f2bf_n((v[3]-mean)*rstd*g2[t*4+3] + beta2[t*4+3]);
    *reinterpret_cast<ushort4*>(&hout[(size_t)r * DM + t * 4]) = o;
}

// ---------------- FFN merge: out = P0 + P1 + b2 + x2 ----------------
__global__ __launch_bounds__(256) void merge_kernel(const unsigned short* __restrict__ P0,
                                                    const unsigned short* __restrict__ P1,
                                                    const float* __restrict__ b2,
                                                    const unsigned short* __restrict__ x2,
                                                    float* __restrict__ out) {
    const size_t i4 = ((size_t)blockIdx.x * 256 + threadIdx.x) * 4;
    const int c = (int)(i4 & 1023);
    ushort4 p0 = *(const ushort4*)&P0[i4];
    ushort4 p1 = *(const ushort4*)&P1[i4];
    ushort4 xx = *(const ushort4*)&x2[i4];
    float4 bb = *(const float4*)&b2[c];
    float4 o;
    o.x = bf2f(p0.x) + bf2f(p1.x) + bb.x + bf2f(xx.x);
    o.y = bf2f(p0.y) + bf2f(p1.y) + bb.y + bf2f(xx.y);
    o.z = bf2f(p0.z) + bf2f(p1.z) + bb.z + bf2f(xx.z);
    o.w = bf2f(p0.w) + bf2f(p1.w) + bb.w + bf2f(xx.w);
    *(float4*)&out[i4] = o;
}

// ============ m97-style GEMM, STAGE-AHEAD DOUBLE BUFFER (T3 minimum 2-phase) ============
// MODE: 0 ->bf16+bias; 1 +resid->bf16; 2 gelu2->bf16; 3 +bias+resid->f32; 5 ->bf16 no bias
// SELMODE: 0 = grid.z selects weight/bias/out triple; 1 = grid.z selects K-half + partial out
template<int MODE, int TN, int SELMODE>
__global__ __launch_bounds__(256) void gemm_gl(
    const unsigned short* __restrict__ A,
    const unsigned short* __restrict__ Wta, const unsigned short* __restrict__ Wtb,
    const unsigned short* __restrict__ Wtc,
    const float* __restrict__ ba, const float* __restrict__ bbb, const float* __restrict__ bc,
    const unsigned short* __restrict__ resid,
    unsigned short* __restrict__ oa, unsigned short* __restrict__ ob,
    unsigned short* __restrict__ oc,
    float* __restrict__ outF,
    int M, int N, int K, int lda, int ldk)
{
    constexpr int CR  = 128 + TN;
    constexpr int RPW = CR / 4;
    constexpr int NI  = RPW / 8;
    constexpr int WAVE_N = (TN == 128) ? 2 : 1;
    constexpr int WAVE_M = 4 / WAVE_N;
    constexpr int AM = 128 / (WAVE_M * 16);
    constexpr int AN = TN / (WAVE_N * 16);
    constexpr int BUF = CR * 64;

    __shared__ unsigned short LDSu[2 * BUF];

    const int gx = gridDim.x, gy = gridDim.y;
    const int nwg = gx * gy * gridDim.z;
    const int wid = blockIdx.x + gx * (blockIdx.y + gy * blockIdx.z);
    const int aid = (wid & 7) * (nwg >> 3) + (wid >> 3);
    const int plane = gx * gy;
    const int sel = aid / plane;
    const int pid = aid % plane;
    const int by = pid % gy;
    const int bx = pid / gy;

    const unsigned short* Wt;
    const float* bias;
    unsigned short* outB;
    int koff;
    if (SELMODE == 0) {
        Wt = (sel == 0) ? Wta : (sel == 1) ? Wtb : Wtc;
        bias = (sel == 0) ? ba : (sel == 1) ? bbb : bc;
        outB = (sel == 0) ? oa : (sel == 1) ? ob : oc;
        koff = 0;
    } else {
        Wt = Wta; bias = ba;
        outB = (sel == 0) ? oa : ob;
        koff = sel * K;
    }

    const int t = threadIdx.x;
    const int lane = t & 63;
    const int w = t >> 6;
    const int l15 = lane & 15, l4 = lane >> 4;
    const int wm = w / WAVE_N, wn = w % WAVE_N;
    const int m0 = by * 128, n0 = bx * TN;

    f32x4 acc[AM][AN];
    #pragma unroll
    for (int i = 0; i < AM; ++i)
        #pragma unroll
        for (int j = 0; j < AN; ++j)
            #pragma unroll
            for (int r = 0; r < 4; ++r) acc[i][j][r] = 0.0f;

    const int gg = (lane & 7) ^ (lane >> 3);
    const unsigned short* gp[NI];
    unsigned short* lp[NI];
    #pragma unroll
    for (int i = 0; i < NI; ++i) {
        const int cr = w * RPW + i * 8 + (lane >> 3);
        gp[i] = (cr < 128) ? (A + (size_t)(m0 + cr) * lda + koff + gg * 8)
                           : (Wt + (size_t)(n0 + cr - 128) * ldk + koff + gg * 8);
        lp[i] = LDSu + (w * RPW + i * 8) * 64;
    }

    const int NT = K / 64;
    // prologue: tile 0 -> buf 0
    #pragma unroll
    for (int i = 0; i < NI; ++i) gl_lds16(gp[i], lp[i]);
    __syncthreads();

    for (int kt = 0; kt < NT; ++kt) {
        const int cur = kt & 1;
        // stage-ahead: issue tile kt+1 into the other buffer BEFORE compute
        if (kt + 1 < NT) {
            const int k0 = (kt + 1) * 64;
            const int nxo = (cur ^ 1) * BUF;
            #pragma unroll
            for (int i = 0; i < NI; ++i) gl_lds16(gp[i] + k0, lp[i] + nxo);
        }
        // compute on buf[cur] (loads for kt+1 in flight underneath)
        const unsigned short* Lb = LDSu + cur * BUF;
        #pragma unroll
        for (int kk = 0; kk < 2; ++kk) {
            const int slot = ((kk * 4 + l4) ^ (l15 & 7)) * 8;
            bf16x8 af[AM], bfr[AN];
            #pragma unroll
            for (int mt = 0; mt < AM; ++mt) {
                const int row = wm * (AM * 16) + mt * 16 + l15;
                u16x8 tmp = *(const u16x8*)(Lb + row * 64 + slot);
                af[mt] = __builtin_bit_cast(bf16x8, tmp);
            }
            #pragma unroll
            for (int nt = 0; nt < AN; ++nt) {
                const int row = 128 + wn * (AN * 16) + nt * 16 + l15;
                u16x8 tmp = *(const u16x8*)(Lb + row * 64 + slot);
                bfr[nt] = __builtin_bit_cast(bf16x8, tmp);
            }
            #pragma unroll
            for (int mt = 0; mt < AM; ++mt)
                #pragma unroll
                for (int nt = 0; nt < AN; ++nt)
                    acc[mt][nt] = __builtin_amdgcn_mfma_f32_16x16x32_bf16(
                        af[mt], bfr[nt], acc[mt][nt], 0, 0, 0);
        }
        if (kt + 1 < NT) __syncthreads();   // drains stage; next buf ready
    }

    #pragma unroll
    for (int mt = 0; mt < AM; ++mt) {
        const int mbase = m0 + wm * (AM * 16) + mt * 16 + l4 * 4;
        #pragma unroll
        for (int nt = 0; nt < AN; ++nt) {
            const int n = n0 + wn * (AN * 16) + nt * 16 + l15;
            const float bs = (MODE == 5) ? 0.0f : bias[n];
            #pragma unroll
            for (int r = 0; r < 4; ++r) {
                const int m = mbase + r;
                float v = acc[mt][nt][r] + bs;
                if (MODE == 2) v = v / (1.0f + expf(-1.702f * v));
                if (MODE == 1 || MODE == 3) v += bf2f(resid[(size_t)m * N + n]);
                if (MODE == 3) outF[(size_t)m * N + n] = v;
                else           outB[(size_t)m * N + n] = f2bf_n(v);
            }
        }
    }
}

// ---------- MFMA flash attention (verified) ----------
#define QB2 32
#define AKT 64
#define KROW 72
#define VROW 72
#define PROW 72
#define SBPIT 72

__global__ __launch_bounds__(128) void attn_mfma(const unsigned short* __restrict__ qbuf,
                                                 const unsigned short* __restrict__ kbuf,
                                                 const unsigned short* __restrict__ vbuf,
                                                 const float* __restrict__ attb,
                                                 const int* __restrict__ mask,
                                                 unsigned short* __restrict__ ctx) {
    __shared__ unsigned short Ks[AKT * KROW];
    __shared__ unsigned short Vt[DH * VROW];
    __shared__ unsigned short Pb[2 * 16 * PROW];
    __shared__ unsigned short Sb[QB2 * SBPIT];
    const int t = threadIdx.x;
    const int lane = t & 63;
    const int w = t >> 6;
    const int l15 = lane & 15, l4 = lane >> 4;
    const int q0 = blockIdx.x * QB2;
    const int h = blockIdx.y;
    const int b = blockIdx.z;

    bf16x8 qf[2];
    {
        const unsigned short* qrow = qbuf + ((size_t)(b * SEQ + q0 + w * 16 + l15)) * DM + h * DH;
        u16x8 t0 = *(const u16x8*)(qrow + l4 * 8);
        u16x8 t1 = *(const u16x8*)(qrow + 32 + l4 * 8);
        qf[0] = __builtin_bit_cast(bf16x8, t0);
        qf[1] = __builtin_bit_cast(bf16x8, t1);
    }

    float m[4] = {-1e30f, -1e30f, -1e30f, -1e30f};
    float l[4] = {0.0f, 0.0f, 0.0f, 0.0f};
    f32x4 o[4];
    #pragma unroll
    for (int dt = 0; dt < 4; ++dt)
        #pragma unroll
        for (int r = 0; r < 4; ++r) o[dt][r] = 0.0f;

    unsigned short* Pw = Pb + w * 16 * PROW;

    const int kr = t >> 1, c0 = (t & 1) * 32;
    const int kp = t & 31, vg = t >> 5;

    u16x8 rk0, rk1, rk2, rk3, rv0, rv1, rv2, rv3;
    float4 rb[4];
    int4   rm[4];

#define LOADT(KT) {                                                                     \
    const int kbase = (KT) * AKT;                                                       \
    const unsigned short* gk = kbuf + ((size_t)(b * SEQ + kbase + kr)) * DM + h * DH + c0; \
    rk0 = *(const u16x8*)gk;        rk1 = *(const u16x8*)(gk + 8);                      \
    rk2 = *(const u16x8*)(gk + 16); rk3 = *(const u16x8*)(gk + 24);                     \
    const unsigned short* gv = vbuf + ((size_t)(b * SEQ + kbase + 2 * kp)) * DM + h * DH + vg * 8; \
    rv0 = *(const u16x8*)gv;        rv1 = *(const u16x8*)(gv + DM);                     \
    rv2 = *(const u16x8*)(gv + 32); rv3 = *(const u16x8*)(gv + DM + 32);                \
    const float* bp = attb + (((size_t)(b * NH + h)) * SEQ + (q0 + w * 16)) * SEQ + kbase; \
    const int* mp = mask + ((size_t)(b * SEQ) + q0 + w * 16) * SEQ + kbase;             \
    _Pragma("unroll")                                                                   \
    for (int i = 0; i < 4; ++i) {                                                       \
        const int e = lane + i * 64; const int row = e >> 4, cg = e & 15;               \
        rb[i] = *(const float4*)&bp[(size_t)row * SEQ + cg * 4];                        \
        rm[i] = *(const int4*)&mp[(size_t)row * SEQ + cg * 4];                          \
    } }

#define STORET() {                                                                      \
    unsigned short* s = Ks + kr * KROW + c0;                                            \
    *(u16x8*)s = rk0; *(u16x8*)(s + 8) = rk1;                                           \
    *(u16x8*)(s + 16) = rk2; *(u16x8*)(s + 24) = rk3;                                   \
    unsigned int* vt32 = (unsigned int*)Vt;                                             \
    _Pragma("unroll")                                                                   \
    for (int j = 0; j < 8; ++j) {                                                       \
        vt32[(vg * 8 + j) * (VROW / 2) + kp] =                                          \
            (unsigned int)rv0[j] | ((unsigned int)rv1[j] << 16);                        \
        vt32[((vg + 4) * 8 + j) * (VROW / 2) + kp] =                                    \
            (unsigned int)rv2[j] | ((unsigned int)rv3[j] << 16);                        \
    }                                                                                   \
    _Pragma("unroll")                                                                   \
    for (int i = 0; i < 4; ++i) {                                                       \
        const int e = lane + i * 64; const int row = e >> 4, cg = e & 15;               \
        ushort4 cc;                                                                     \
        cc.x = f2bf_n(rm[i].x ? -8e30f : 8.0f * rb[i].x);                               \
        cc.y = f2bf_n(rm[i].y ? -8e30f : 8.0f * rb[i].y);                               \
        cc.z = f2bf_n(rm[i].z ? -8e30f : 8.0f * rb[i].z);                               \
        cc.w = f2bf_n(rm[i].w ? -8e30f : 8.0f * rb[i].w);                               \
        *(ushort4*)&Sb[(w * 16 + row) * SBPIT + cg * 4] = cc;                           \
    } }

    LOADT(0);
    for (int kt = 0; kt < SEQ / AKT; ++kt) {
        __syncthreads();
        STORET();
        __syncthreads();
        if (kt + 1 < SEQ / AKT) LOADT(kt + 1);

        f32x4 acc[4];
        #pragma unroll
        for (int nt = 0; nt < 4; ++nt)
            #pragma unroll
            for (int r = 0; r < 4; ++r)
                acc[nt][r] = bf2f(Sb[(w * 16 + l4 * 4 + r) * SBPIT + nt * 16 + l15]);

        #pragma unroll
        for (int kk = 0; kk < 2; ++kk) {
            #pragma unroll
            for (int nt = 0; nt < 4; ++nt) {
                u16x8 tmp = *(const u16x8*)(Ks + (nt * 16 + l15) * KROW + kk * 32 + l4 * 8);
                acc[nt] = __builtin_amdgcn_mfma_f32_16x16x32_bf16(
                    qf[kk], __builtin_bit_cast(bf16x8, tmp), acc[nt], 0, 0, 0);
            }
        }

        float pm[4] = {-1e30f, -1e30f, -1e30f, -1e30f};
        #pragma unroll
        for (int nt = 0; nt < 4; ++nt) {
            #pragma unroll
            for (int r = 0; r < 4; ++r) {
                const float sv = acc[nt][r] * 0.125f;
                acc[nt][r] = sv;
                pm[r] = fmaxf(pm[r], sv);
            }
        }
        #pragma unroll
        for (int r = 0; r < 4; ++r) {
            #pragma unroll
            for (int off = 1; off < 16; off <<= 1)
                pm[r] = fmaxf(pm[r], __shfl_xor(pm[r], off));
        }
        float al[4], ps[4];
        #pragma unroll
        for (int r = 0; r < 4; ++r) {
            const float mn = fmaxf(m[r], pm[r]);
            al[r] = __expf(m[r] - mn);
            m[r] = mn;
            ps[r] = 0.0f;
        }
        #pragma unroll
        for (int nt = 0; nt < 4; ++nt) {
            #pragma unroll
            for (int r = 0; r < 4; ++r) {
                const float p = __expf(acc[nt][r] - m[r]);
                acc[nt][r] = p;
                ps[r] += p;
            }
        }
        #pragma unroll
        for (int r = 0; r < 4; ++r) {
            #pragma unroll
            for (int off = 1; off < 16; off <<= 1) ps[r] += __shfl_xor(ps[r], off);
            l[r] = l[r] * al[r] + ps[r];
        }
        #pragma unroll
        for (int dt = 0; dt < 4; ++dt)
            #pragma unroll
            for (int r = 0; r < 4; ++r) o[dt][r] *= al[r];

        #pragma unroll
        for (int nt = 0; nt < 4; ++nt)
            #pragma unroll
            for (int r = 0; r < 4; ++r)
                Pw[(l4 * 4 + r) * PROW + nt * 16 + l15] = f2bf_n(acc[nt][r]);

        #pragma unroll
        for (int ks = 0; ks < 2; ++ks) {
            u16x8 pa = *(const u16x8*)(Pw + l15 * PROW + ks * 32 + l4 * 8);
            #pragma unroll
            for (int dt = 0; dt < 4; ++dt) {
                u16x8 vv = *(const u16x8*)(Vt + (dt * 16 + l15) * VROW + ks * 32 + l4 * 8);
                o[dt] = __builtin_amdgcn_mfma_f32_16x16x32_bf16(
                    __builtin_bit_cast(bf16x8, pa), __builtin_bit_cast(bf16x8, vv),
                    o[dt], 0, 0, 0);
            }
        }
    }

    #pragma unroll
    for (int r = 0; r < 4; ++r) {
        const float inv = 1.0f / l[r];
        const size_t row = (size_t)(b * SEQ + q0 + w * 16 + l4 * 4 + r) * DM + h * DH;
        #pragma unroll
        for (int dt = 0; dt < 4; ++dt)
            ctx[row + dt * 16 + l15] = f2bf_n(o[dt][r] * inv);
    }
#undef LOADT
#undef STORET
}

// ---------------- host launch ----------------
extern "C" void kernel_launch(void* const* d_in, const int* in_sizes, int n_in,
                              void* d_out, int out_size, void* d_ws, size_t ws_size,
                              hipStream_t stream) {
    const float* src  = (const float*)d_in[0];
    const int*   mask = (const int*)d_in[1];
    const int*   ts   = (const int*)d_in[2];
    const float* attb = (const float*)d_in[3];
    const float* Wada = (const float*)d_in[4];
    const float* bada = (const float*)d_in[5];
    const float* Wq   = (const float*)d_in[6];
    const float* bq   = (const float*)d_in[7];
    const float* Wk   = (const float*)d_in[8];
    const float* bk   = (const float*)d_in[9];
    const float* Wv   = (const float*)d_in[10];
    const float* bv   = (const float*)d_in[11];
    const float* Wo   = (const float*)d_in[12];
    const float* bo   = (const float*)d_in[13];
    const float* W1   = (const float*)d_in[14];
    const float* b1   = (const float*)d_in[15];
    const float* W2   = (const float*)d_in[16];
    const float* b2   = (const float*)d_in[17];
    const float* g2   = (const float*)d_in[18];
    const float* bt2  = (const float*)d_in[19];
    float* out = (float*)d_out;

    const size_t MB = 1024 * 1024;
    const size_t NEED_FULL = 65536 + 52 * MB;   // proven available
    if (ws_size < NEED_FULL) {
        fill0_kernel<<<(size_t)MROWS * DM / 256, 256, 0, stream>>>(out);
        return;
    }

    char* ws = (char*)d_ws;
    float* semb = (float*)(ws + 4096);
    float* ss   = (float*)(ws + 24576);
    char*  base = ws + 65536;
    unsigned short* slotA = (unsigned short*)(base);
    unsigned short* slotB = (unsigned short*)(base + 4 * MB);
    unsigned short* slotC = (unsigned short*)(base + 8 * MB);
    unsigned short* vb   = (unsigned short*)d_out;
    unsigned short* ctxb = (unsigned short*)((char*)d_out + 4 * MB);
    unsigned short* xb = slotA;
    unsigned short* qb = slotB;
    unsigned short* kb = slotC;
    unsigned short* x2 = slotB;
    unsigned short* hb = slotC;
    unsigned short* P0 = slotA;   // W2 partial 0 (xb dead after Wo)
    unsigned short* P1 = slotC;   // W2 partial 1 (hb dead after W1)
    float* adap = (float*)slotC;

    unsigned short* Wtq = (unsigned short*)(base + 12 * MB);
    unsigned short* Wtk = Wtq + 1024 * 1024;
    unsigned short* Wtv = Wtk + 1024 * 1024;
    unsigned short* Wto = Wtv + 1024 * 1024;
    unsigned short* Wt1 = Wto + 1024 * 1024;               // [4096][1024]
    unsigned short* Wt2 = Wt1 + (size_t)4096 * 1024;       // [1024][4096]
    unsigned short* midF = (unsigned short*)(base + 36 * MB);  // [2048][4096]

    tconv4_kernel<<<dim3(32, 16, 4), 256, 0, stream>>>(Wq, Wk, Wv, Wo, Wtq, Wtk, Wtv, Wto);
    tconv_kernel<<<dim3(128, 16), 256, 0, stream>>>(W1, Wt1, 1024, 4096);
    tconv_kernel<<<dim3(32, 64), 256, 0, stream>>>(W2, Wt2, 4096, 1024);

    semb_kernel<<<4, 256, 0, stream>>>(ts, semb);
    ada_part_kernel<<<dim3(16, 16), 256, 0, stream>>>(semb, Wada, adap);
    ada_red_kernel<<<32, 256, 0, stream>>>(adap, bada, ss);
    adaln_kernel<<<MROWS, 256, 0, stream>>>(src, ss, xb);

    // QKV fused (grid.z selects weight/bias/out)
    gemm_gl<0, 128, 0><<<dim3(8, 16, 3), 256, 0, stream>>>(
        xb, Wtq, Wtk, Wtv, bq, bk, bv, nullptr, qb, kb, vb, nullptr,
        MROWS, DM, DM, DM, DM);
    attn_mfma<<<dim3(SEQ / QB2, NH, BATCH), 128, 0, stream>>>(qb, kb, vb, attb, mask, ctxb);
    // x2 = xb + ctx@Wo + bo
    gemm_gl<1, 64, 0><<<dim3(16, 16), 256, 0, stream>>>(
        ctxb, Wto, Wto, Wto, bo, bo, bo, xb, x2, x2, x2, nullptr,
        MROWS, DM, DM, DM, DM);
    ln2_kernel<<<MROWS, 256, 0, stream>>>(x2, g2, bt2, hb);
    // FFN: mid = gelu2(h@W1+b1)
    gemm_gl<2, 128, 0><<<dim3(32, 16), 256, 0, stream>>>(
        hb, Wt1, Wt1, Wt1, b1, b1, b1, nullptr, midF, midF, midF, nullptr,
        MROWS, DFF, DM, DM, DM);
    // W2 K-split: z=0 -> P0 (K 0..2047), z=1 -> P1 (K 2048..4095), bf16 partials
    gemm_gl<5, 128, 1><<<dim3(8, 16, 2), 256, 0, stream>>>(
        midF, Wt2, Wt2, Wt2, b2, b2, b2, nullptr, P0, P1, nullptr, nullptr,
        MROWS, DM, 2048, DFF, DFF);
    // out = P0 + P1 + b2 + x2
    merge_kernel<<<(size_t)MROWS * DM / 1024, 256, 0, stream>>>(P0, P1, b2, x2, out);
}